// Round 4
// baseline (16405.736 us; speedup 1.0000x reference)
//
#include <hip/hip_runtime.h>

// Output layout (flat f32, reference return order):
//   xhat  : B*L*N   = 13,107,200  @ 0
//   mu    : B*D     =      4,096  @ 13,107,200
//   logvar: B*D     =      4,096  @ 13,111,296
//   z_traj: B*L*D   =    819,200  @ 13,115,392
//   zdiff : B*(L-1)*D =  815,104  @ 13,934,592
#define OFF_MU   13107200
#define OFF_LV   13111296
#define OFF_ZT   13115392
#define OFF_ZD   13934592

typedef float v2f __attribute__((ext_vector_type(2)));

__device__ __forceinline__ float silu_f(float x) {
    return x / (1.0f + __expf(-x));
}

__device__ __forceinline__ float readlane_f(float v, int l) {
    return __uint_as_float(__builtin_amdgcn_readlane(__float_as_uint(v), l));
}

__device__ __forceinline__ v2f fma2(v2f a, v2f b, v2f c) {
    return __builtin_elementwise_fma(a, b, c);
}

// x + dpp_move(x) with compile-time DPP control. VALU-latency cross-lane.
template <int CTRL>
__device__ __forceinline__ float dppadd(float x) {
    int y = __builtin_amdgcn_update_dpp(0, __float_as_int(x), CTRL, 0xF, 0xF, true);
    return x + __int_as_float(y);
}

// Sum of x over each 16-lane row (values replicated per row afterwards).
__device__ __forceinline__ float sum16_dpp(float x) {
    x = dppadd<0xB1>(x);    // quad_perm xor1
    x = dppadd<0x4E>(x);    // quad_perm xor2
    x = dppadd<0x141>(x);   // row_half_mirror (xor4 once quad-uniform)
    x = dppadd<0x140>(x);   // row_mirror (xor8 once 8-uniform)
    return x;
}

// ---------------------------------------------------------------------------
// Encoder: one block per batch row. x0(256) -> 512 -> 256 -> 128 -> mu/lv(16)
// (unchanged — negligible cost)
// ---------------------------------------------------------------------------
__global__ __launch_bounds__(256) void enc_kernel(
    const float* __restrict__ xseq, const float* __restrict__ eps,
    const float* __restrict__ w1, const float* __restrict__ b1,
    const float* __restrict__ w2, const float* __restrict__ b2,
    const float* __restrict__ w3, const float* __restrict__ b3,
    const float* __restrict__ muw, const float* __restrict__ mub,
    const float* __restrict__ lvw, const float* __restrict__ lvb,
    float* __restrict__ out)
{
    __shared__ float xr[256];
    __shared__ float h1[512];
    __shared__ float h2[256];
    __shared__ float h3[128];

    const int t = threadIdx.x;
    const int b = blockIdx.x;

    xr[t] = xseq[b * (200 * 256) + t];
    __syncthreads();

    {
        float acc0 = b1[t], acc1 = b1[t + 256];
        for (int i = 0; i < 256; ++i) {
            float xv = xr[i];
            acc0 = fmaf(xv, w1[i * 512 + t],       acc0);
            acc1 = fmaf(xv, w1[i * 512 + t + 256], acc1);
        }
        h1[t]       = fmaxf(acc0, 0.0f);
        h1[t + 256] = fmaxf(acc1, 0.0f);
    }
    __syncthreads();

    {
        float acc = b2[t];
        for (int i = 0; i < 512; ++i) acc = fmaf(h1[i], w2[i * 256 + t], acc);
        h2[t] = fmaxf(acc, 0.0f);
    }
    __syncthreads();

    if (t < 128) {
        float acc = b3[t];
        for (int i = 0; i < 256; ++i) acc = fmaf(h2[i], w3[i * 128 + t], acc);
        h3[t] = fmaxf(acc, 0.0f);
    }
    __syncthreads();

    if (t < 16) {
        float mu = mub[t], lv = lvb[t];
        for (int i = 0; i < 128; ++i) {
            float hv = h3[i];
            mu = fmaf(hv, muw[i * 16 + t], mu);
            lv = fmaf(hv, lvw[i * 16 + t], lv);
        }
        out[OFF_MU + b * 16 + t] = mu;
        out[OFF_LV + b * 16 + t] = lv;
        float z0 = mu + __expf(0.5f * lv) * eps[b * 16 + t];
        out[OFF_ZT + b * 3200 + t] = z0;
    }
}

// ---------------------------------------------------------------------------
// ODE integrator v5: ONE WAVE per batch element.
//   v3/v4 post-mortem: per-lane weight demand (160+ VGPR) exceeds what the
//   allocator will grant (~132); overflow became per-feval L2/scratch reloads
//   (~1800 stall cyc/feval). Structural fix: w2 (the 256 floats/lane that can
//   never fit) lives ENTIRELY in LDS as packed float4 — deterministic ~300clk
//   per feval, no reload traffic. Register demand drops to ~105 so w1/w3
//   stay truly resident. zarg broadcast via readlane->SGPR (no LDS round
//   trip). a2 partials in a padded buffer (stride 36) for conflict-free L3.
// ---------------------------------------------------------------------------
__global__ __launch_bounds__(64, 1) void ode_kernel(
    const float* __restrict__ tvec,
    const float* __restrict__ ow1, const float* __restrict__ ob1,
    const float* __restrict__ ow2, const float* __restrict__ ob2,
    const float* __restrict__ ow3, const float* __restrict__ ob3,
    const float* __restrict__ lng, const float* __restrict__ lnb,
    float* __restrict__ out)
{
    __shared__ __align__(16) float4 w2l[64 * 64];   // 64 KB: all of w2, packed
    __shared__ __align__(16) float  a1s[128];
    __shared__ __align__(16) float  a2p[4 * 36];    // 4 chunks of 32, pad 4

    const int lane = threadIdx.x;
    const int b    = blockIdx.x;
    const int d    = lane & 15;      // owned z-dim (replicated x4)
    const int g    = lane >> 4;      // replication group / L3 K-chunk
    const int l64  = lane + 64;

    // ---- stage ALL of w2 into LDS, packed {k0,k1}x{j,j+64} ----------------
    // w2l[kp*64 + j] = { w2[2kp][j], w2[2kp+1][j], w2[2kp][j+64], w2[2kp+1][j+64] }
    for (int kp = 0; kp < 64; ++kp) {
        float4 val;
        val.x = ow2[(2 * kp) * 128 + lane];
        val.y = ow2[(2 * kp + 1) * 128 + lane];
        val.z = ow2[(2 * kp) * 128 + l64];
        val.w = ow2[(2 * kp + 1) * 128 + l64];
        w2l[kp * 64 + lane] = val;
    }

    // ---- register-resident small weights (volatile: loaded exactly once) --
    const volatile float* vw1 = ow1;
    const volatile float* vw3 = ow3;

    float w1r0[16], w1r1[16];
#pragma unroll
    for (int k = 0; k < 16; ++k) {
        w1r0[k] = vw1[k * 128 + lane];
        w1r1[k] = vw1[k * 128 + l64];
    }
    v2f w3r[16];   // K-chunk g (32 wide), stored in bank-staggered read order
#pragma unroll
    for (int qq = 0; qq < 8; ++qq) {
        int qsel = (qq + 2 * g) & 7;
        int k0   = 32 * g + 4 * qsel;
        v2f t0 = { vw3[(k0 + 0) * 16 + d], vw3[(k0 + 1) * 16 + d] };
        v2f t1 = { vw3[(k0 + 2) * 16 + d], vw3[(k0 + 3) * 16 + d] };
        w3r[2 * qq]     = t0;
        w3r[2 * qq + 1] = t1;
    }
    const volatile float* vb1 = ob1;
    const volatile float* vb2 = ob2;
    const volatile float* vb3 = ob3;
    const volatile float* vlg = lng;
    const volatile float* vlb = lnb;
    const float b1j0 = vb1[lane], b1j1 = vb1[l64];
    const float b2j0 = vb2[lane], b2j1 = vb2[l64];
    const float b3d  = vb3[d];
    const float lngd = vlg[d], lnbd = vlb[d];

    float* ztraj = out + OFF_ZT + b * 3200;   // [200][16]
    float* zdiff = out + OFF_ZD + b * 3184;   // [199][16]

    __syncthreads();                          // w2l staged (WG==wave)

    float z = ztraj[d];                       // z0, replicated x4

    // one evaluation of f(za); za = zarg[d] per lane (replicated x4).
    auto feval = [&](float za) -> float {
        // L1: zarg broadcast via readlane (lanes 0..15 hold all 16 dims).
        // Two accumulator chains per column to halve dependent latency.
        float a0e = 0.0f, a0o = 0.0f, a1e = 0.0f, a1o = 0.0f;
#pragma unroll
        for (int k = 0; k < 16; k += 2) {
            float zk0 = readlane_f(za, k);
            float zk1 = readlane_f(za, k + 1);
            a0e = fmaf(zk0, w1r0[k],     a0e);
            a1e = fmaf(zk0, w1r1[k],     a1e);
            a0o = fmaf(zk1, w1r0[k + 1], a0o);
            a1o = fmaf(zk1, w1r1[k + 1], a1o);
        }
        a1s[lane] = silu_f(a0e + a0o + b1j0);
        a1s[l64]  = silu_f(a1e + a1o + b1j1);
        __syncthreads();

        // L2: K=128 as 64 kpairs, all weights from LDS (b128 each),
        // a1 via broadcast b128 reads (2 kpairs per read).
        v2f A0 = {0.0f, 0.0f}, A1 = {0.0f, 0.0f};   // col j: even/odd kpair
        v2f B0 = {0.0f, 0.0f}, B1 = {0.0f, 0.0f};   // col j+64
        const float4* a14 = (const float4*)a1s;
#pragma unroll
        for (int q4 = 0; q4 < 32; ++q4) {
            float4 av  = a14[q4];                     // a1[4q4 .. 4q4+3]
            float4 w0  = w2l[q4 * 128 + lane];        // kpair 2q4
            float4 w1v = w2l[q4 * 128 + 64 + lane];   // kpair 2q4+1
            v2f plo = { av.x, av.y };
            v2f phi = { av.z, av.w };
            A0 = fma2(plo, (v2f){ w0.x,  w0.y  }, A0);
            B0 = fma2(plo, (v2f){ w0.z,  w0.w  }, B0);
            A1 = fma2(phi, (v2f){ w1v.x, w1v.y }, A1);
            B1 = fma2(phi, (v2f){ w1v.z, w1v.w }, B1);
        }
        float a20 = silu_f(A0.x + A0.y + A1.x + A1.y + b2j0);
        float a21 = silu_f(B0.x + B0.y + B1.x + B1.y + b2j1);
        a2p[((lane >> 5)) * 36 + (lane & 31)]       = a20;
        a2p[((l64  >> 5)) * 36 + (l64  & 31)]       = a21;
        __syncthreads();

        // L3: output d, K-chunk g (32 wide); padded stride 36 => groups hit
        // disjoint banks; qsel rotation staggers within-group reads.
        v2f pp = {0.0f, 0.0f};
#pragma unroll
        for (int qq = 0; qq < 8; ++qq) {
            int qsel = (qq + 2 * g) & 7;
            float4 av = *(const float4*)&a2p[g * 36 + 4 * qsel];
            pp = fma2((v2f){ av.x, av.y }, w3r[2 * qq],     pp);
            pp = fma2((v2f){ av.z, av.w }, w3r[2 * qq + 1], pp);
        }
        // combine 4 K-chunks across lane groups (xor16 then xor32)
        float pd = pp.x + pp.y;
        pd += __shfl_xor(pd, 16);
        pd += __shfl_xor(pd, 32);
        float dz = pd + b3d;

        // LayerNorm over d=0..15 via DPP row sums (replicated result)
        float m  = sum16_dpp(dz) * 0.0625f;
        float df = dz - m;
        float v  = sum16_dpp(df * df) * 0.0625f;
        return df * rsqrtf(v + 1e-5f) * lngd + lnbd;
    };

    for (int l = 0; l < 199; ++l) {
        const float dt = tvec[l + 1] - tvec[l];
        const float h  = dt * 0.125f;          // dt / K, K=8 (exact)
        const float zstart = z;
        for (int s = 0; s < 8; ++s) {
            float k1 = feval(z);
            float k2 = feval(z + h * (k1 * (float)(1.0 / 5.0)));
            float k3 = feval(z + h * ((float)(3.0 / 40.0) * k1 + (float)(9.0 / 40.0) * k2));
            float k4 = feval(z + h * ((float)(44.0 / 45.0) * k1 - (float)(56.0 / 15.0) * k2
                                    + (float)(32.0 / 9.0) * k3));
            float k5 = feval(z + h * ((float)(19372.0 / 6561.0) * k1 - (float)(25360.0 / 2187.0) * k2
                                    + (float)(64448.0 / 6561.0) * k3 - (float)(212.0 / 729.0) * k4));
            float k6 = feval(z + h * ((float)(9017.0 / 3168.0) * k1 - (float)(355.0 / 33.0) * k2
                                    + (float)(46732.0 / 5247.0) * k3 + (float)(49.0 / 176.0) * k4
                                    - (float)(5103.0 / 18656.0) * k5));
            z = z + h * ((float)(35.0 / 384.0) * k1 + (float)(500.0 / 1113.0) * k3
                       + (float)(125.0 / 192.0) * k4 - (float)(2187.0 / 6784.0) * k5
                       + (float)(11.0 / 84.0) * k6);
        }
        if (lane < 16) {
            ztraj[(l + 1) * 16 + lane] = z;
            zdiff[l * 16 + lane] = (z - zstart) / dt;
        }
    }
}

// ---------------------------------------------------------------------------
// Decoder: fused 3-layer MLP over 51200 rows. M-tile=16, 256 threads.
// Change: launch_bounds (256,4) — 4 blocks/CU to hide the L2-bound w2 reads.
// ---------------------------------------------------------------------------
#define GS 516   // padded LDS stride for the 16x512 activation tile

__global__ __launch_bounds__(256, 4) void dec_kernel(
    const float* __restrict__ ztr,
    const float* __restrict__ w1, const float* __restrict__ b1,
    const float* __restrict__ w2, const float* __restrict__ b2,
    const float* __restrict__ w3, const float* __restrict__ b3,
    float* __restrict__ xhat)
{
    __shared__ __align__(16) float zt[16 * 17];
    __shared__ __align__(16) float g[16 * GS];

    const int t    = threadIdx.x;
    const int blk  = blockIdx.x;
    const int tr   = t >> 5;
    const int tc   = t & 31;
    const int row0 = blk * 16;
    const int r0   = 2 * tr;

    {
        int r = t >> 4, dd = t & 15;
        zt[r * 17 + dd] = ztr[(row0 + r) * 16 + dd];
    }
    __syncthreads();

    // Phase A: g1 = relu(z @ w1 + b1), K=16
    {
        float acc[2][16];
#pragma unroll
        for (int p = 0; p < 2; ++p)
#pragma unroll
            for (int i = 0; i < 16; ++i) acc[p][i] = 0.0f;

#pragma unroll
        for (int k = 0; k < 16; ++k) {
            float a0 = zt[(r0 + 0) * 17 + k];
            float a1 = zt[(r0 + 1) * 17 + k];
            const float4* wr = (const float4*)(w1 + k * 512 + 16 * tc);
#pragma unroll
            for (int u = 0; u < 4; ++u) {
                float4 wv = wr[u];
                acc[0][4 * u + 0] = fmaf(a0, wv.x, acc[0][4 * u + 0]);
                acc[0][4 * u + 1] = fmaf(a0, wv.y, acc[0][4 * u + 1]);
                acc[0][4 * u + 2] = fmaf(a0, wv.z, acc[0][4 * u + 2]);
                acc[0][4 * u + 3] = fmaf(a0, wv.w, acc[0][4 * u + 3]);
                acc[1][4 * u + 0] = fmaf(a1, wv.x, acc[1][4 * u + 0]);
                acc[1][4 * u + 1] = fmaf(a1, wv.y, acc[1][4 * u + 1]);
                acc[1][4 * u + 2] = fmaf(a1, wv.z, acc[1][4 * u + 2]);
                acc[1][4 * u + 3] = fmaf(a1, wv.w, acc[1][4 * u + 3]);
            }
        }
        const float4* bb = (const float4*)(b1 + 16 * tc);
#pragma unroll
        for (int u = 0; u < 4; ++u) {
            float4 bv = bb[u];
#pragma unroll
            for (int p = 0; p < 2; ++p) {
                g[(r0 + p) * GS + 16 * tc + 4 * u + 0] = fmaxf(acc[p][4 * u + 0] + bv.x, 0.0f);
                g[(r0 + p) * GS + 16 * tc + 4 * u + 1] = fmaxf(acc[p][4 * u + 1] + bv.y, 0.0f);
                g[(r0 + p) * GS + 16 * tc + 4 * u + 2] = fmaxf(acc[p][4 * u + 2] + bv.z, 0.0f);
                g[(r0 + p) * GS + 16 * tc + 4 * u + 3] = fmaxf(acc[p][4 * u + 3] + bv.w, 0.0f);
            }
        }
    }
    __syncthreads();

    // Phase B: g2 = relu(g1 @ w2 + b2), K=512
    {
        float accB[2][16];
#pragma unroll
        for (int p = 0; p < 2; ++p)
#pragma unroll
            for (int i = 0; i < 16; ++i) accB[p][i] = 0.0f;

        for (int k4 = 0; k4 < 128; ++k4) {
            float4 av0 = *(const float4*)&g[(r0 + 0) * GS + 4 * k4];
            float4 av1 = *(const float4*)&g[(r0 + 1) * GS + 4 * k4];
            float a0[4] = {av0.x, av0.y, av0.z, av0.w};
            float a1[4] = {av1.x, av1.y, av1.z, av1.w};
#pragma unroll
            for (int u = 0; u < 4; ++u) {
                const float4* wr = (const float4*)(w2 + (4 * k4 + u) * 512 + 16 * tc);
#pragma unroll
                for (int q = 0; q < 4; ++q) {
                    float4 wv = wr[q];
                    accB[0][4 * q + 0] = fmaf(a0[u], wv.x, accB[0][4 * q + 0]);
                    accB[0][4 * q + 1] = fmaf(a0[u], wv.y, accB[0][4 * q + 1]);
                    accB[0][4 * q + 2] = fmaf(a0[u], wv.z, accB[0][4 * q + 2]);
                    accB[0][4 * q + 3] = fmaf(a0[u], wv.w, accB[0][4 * q + 3]);
                    accB[1][4 * q + 0] = fmaf(a1[u], wv.x, accB[1][4 * q + 0]);
                    accB[1][4 * q + 1] = fmaf(a1[u], wv.y, accB[1][4 * q + 1]);
                    accB[1][4 * q + 2] = fmaf(a1[u], wv.z, accB[1][4 * q + 2]);
                    accB[1][4 * q + 3] = fmaf(a1[u], wv.w, accB[1][4 * q + 3]);
                }
            }
        }
        __syncthreads();
        const float4* bb = (const float4*)(b2 + 16 * tc);
#pragma unroll
        for (int u = 0; u < 4; ++u) {
            float4 bv = bb[u];
#pragma unroll
            for (int p = 0; p < 2; ++p) {
                g[(r0 + p) * GS + 16 * tc + 4 * u + 0] = fmaxf(accB[p][4 * u + 0] + bv.x, 0.0f);
                g[(r0 + p) * GS + 16 * tc + 4 * u + 1] = fmaxf(accB[p][4 * u + 1] + bv.y, 0.0f);
                g[(r0 + p) * GS + 16 * tc + 4 * u + 2] = fmaxf(accB[p][4 * u + 2] + bv.z, 0.0f);
                g[(r0 + p) * GS + 16 * tc + 4 * u + 3] = fmaxf(accB[p][4 * u + 3] + bv.w, 0.0f);
            }
        }
    }
    __syncthreads();

    // Phase C: xhat = g2 @ w3 + b3, N=256 (8 cols/thread), K=512
    {
        float accC[2][8];
#pragma unroll
        for (int p = 0; p < 2; ++p)
#pragma unroll
            for (int i = 0; i < 8; ++i) accC[p][i] = 0.0f;

        for (int k4 = 0; k4 < 128; ++k4) {
            float4 av0 = *(const float4*)&g[(r0 + 0) * GS + 4 * k4];
            float4 av1 = *(const float4*)&g[(r0 + 1) * GS + 4 * k4];
            float a0[4] = {av0.x, av0.y, av0.z, av0.w};
            float a1[4] = {av1.x, av1.y, av1.z, av1.w};
#pragma unroll
            for (int u = 0; u < 4; ++u) {
                const float4* wr = (const float4*)(w3 + (4 * k4 + u) * 256 + 8 * tc);
                float4 w0 = wr[0], w1v = wr[1];
                accC[0][0] = fmaf(a0[u], w0.x,  accC[0][0]);
                accC[0][1] = fmaf(a0[u], w0.y,  accC[0][1]);
                accC[0][2] = fmaf(a0[u], w0.z,  accC[0][2]);
                accC[0][3] = fmaf(a0[u], w0.w,  accC[0][3]);
                accC[0][4] = fmaf(a0[u], w1v.x, accC[0][4]);
                accC[0][5] = fmaf(a0[u], w1v.y, accC[0][5]);
                accC[0][6] = fmaf(a0[u], w1v.z, accC[0][6]);
                accC[0][7] = fmaf(a0[u], w1v.w, accC[0][7]);
                accC[1][0] = fmaf(a1[u], w0.x,  accC[1][0]);
                accC[1][1] = fmaf(a1[u], w0.y,  accC[1][1]);
                accC[1][2] = fmaf(a1[u], w0.z,  accC[1][2]);
                accC[1][3] = fmaf(a1[u], w0.w,  accC[1][3]);
                accC[1][4] = fmaf(a1[u], w1v.x, accC[1][4]);
                accC[1][5] = fmaf(a1[u], w1v.y, accC[1][5]);
                accC[1][6] = fmaf(a1[u], w1v.z, accC[1][6]);
                accC[1][7] = fmaf(a1[u], w1v.w, accC[1][7]);
            }
        }
        const float4* bb = (const float4*)(b3 + 8 * tc);
        float4 bv0 = bb[0], bv1 = bb[1];
#pragma unroll
        for (int p = 0; p < 2; ++p) {
            float4 o0 = make_float4(accC[p][0] + bv0.x, accC[p][1] + bv0.y,
                                    accC[p][2] + bv0.z, accC[p][3] + bv0.w);
            float4 o1 = make_float4(accC[p][4] + bv1.x, accC[p][5] + bv1.y,
                                    accC[p][6] + bv1.z, accC[p][7] + bv1.w);
            float* dst = xhat + (size_t)(row0 + r0 + p) * 256 + 8 * tc;
            *(float4*)(dst)     = o0;
            *(float4*)(dst + 4) = o1;
        }
    }
}

extern "C" void kernel_launch(void* const* d_in, const int* in_sizes, int n_in,
                              void* d_out, int out_size, void* d_ws, size_t ws_size,
                              hipStream_t stream) {
    const float* x_seq  = (const float*)d_in[0];
    const float* tvec   = (const float*)d_in[1];
    const float* eps    = (const float*)d_in[2];
    const float* enc_w1 = (const float*)d_in[3];
    const float* enc_b1 = (const float*)d_in[4];
    const float* enc_w2 = (const float*)d_in[5];
    const float* enc_b2 = (const float*)d_in[6];
    const float* enc_w3 = (const float*)d_in[7];
    const float* enc_b3 = (const float*)d_in[8];
    const float* mu_w   = (const float*)d_in[9];
    const float* mu_b   = (const float*)d_in[10];
    const float* lv_w   = (const float*)d_in[11];
    const float* lv_b   = (const float*)d_in[12];
    const float* ode_w1 = (const float*)d_in[13];
    const float* ode_b1 = (const float*)d_in[14];
    const float* ode_w2 = (const float*)d_in[15];
    const float* ode_b2 = (const float*)d_in[16];
    const float* ode_w3 = (const float*)d_in[17];
    const float* ode_b3 = (const float*)d_in[18];
    const float* ln_g   = (const float*)d_in[19];
    const float* ln_b   = (const float*)d_in[20];
    const float* dec_w1 = (const float*)d_in[21];
    const float* dec_b1 = (const float*)d_in[22];
    const float* dec_w2 = (const float*)d_in[23];
    const float* dec_b2 = (const float*)d_in[24];
    const float* dec_w3 = (const float*)d_in[25];
    const float* dec_b3 = (const float*)d_in[26];
    float* out = (float*)d_out;

    enc_kernel<<<256, 256, 0, stream>>>(x_seq, eps, enc_w1, enc_b1, enc_w2, enc_b2,
                                        enc_w3, enc_b3, mu_w, mu_b, lv_w, lv_b, out);
    ode_kernel<<<256, 64, 0, stream>>>(tvec, ode_w1, ode_b1, ode_w2, ode_b2,
                                       ode_w3, ode_b3, ln_g, ln_b, out);
    dec_kernel<<<3200, 256, 0, stream>>>(out + OFF_ZT, dec_w1, dec_b1, dec_w2, dec_b2,
                                         dec_w3, dec_b3, out);
}

// Round 5
// 10710.118 us; speedup vs baseline: 1.5318x; 1.5318x over previous
//
#include <hip/hip_runtime.h>

// Output layout (flat f32, reference return order):
//   xhat  : B*L*N   = 13,107,200  @ 0
//   mu    : B*D     =      4,096  @ 13,107,200
//   logvar: B*D     =      4,096  @ 13,111,296
//   z_traj: B*L*D   =    819,200  @ 13,115,392
//   zdiff : B*(L-1)*D =  815,104  @ 13,934,592
#define OFF_MU   13107200
#define OFF_LV   13111296
#define OFF_ZT   13115392
#define OFF_ZD   13934592

typedef float v2f __attribute__((ext_vector_type(2)));

__device__ __forceinline__ float silu_f(float x) {
    return x / (1.0f + __expf(-x));
}

__device__ __forceinline__ float readlane_f(float v, int l) {
    return __uint_as_float(__builtin_amdgcn_readlane(__float_as_uint(v), l));
}

__device__ __forceinline__ v2f fma2(v2f a, v2f b, v2f c) {
    return __builtin_elementwise_fma(a, b, c);
}

// x + dpp_move(x) with compile-time DPP control. VALU-latency cross-lane.
template <int CTRL>
__device__ __forceinline__ float dppadd(float x) {
    int y = __builtin_amdgcn_update_dpp(0, __float_as_int(x), CTRL, 0xF, 0xF, true);
    return x + __int_as_float(y);
}

// Sum of x over each 16-lane row (values replicated per row afterwards).
__device__ __forceinline__ float sum16_dpp(float x) {
    x = dppadd<0xB1>(x);    // quad_perm xor1
    x = dppadd<0x4E>(x);    // quad_perm xor2
    x = dppadd<0x141>(x);   // row_half_mirror (xor4 once quad-uniform)
    x = dppadd<0x140>(x);   // row_mirror (xor8 once 8-uniform)
    return x;
}

// ---------------------------------------------------------------------------
// Encoder: one block per batch row. x0(256) -> 512 -> 256 -> 128 -> mu/lv(16)
// (unchanged — negligible cost)
// ---------------------------------------------------------------------------
__global__ __launch_bounds__(256) void enc_kernel(
    const float* __restrict__ xseq, const float* __restrict__ eps,
    const float* __restrict__ w1, const float* __restrict__ b1,
    const float* __restrict__ w2, const float* __restrict__ b2,
    const float* __restrict__ w3, const float* __restrict__ b3,
    const float* __restrict__ muw, const float* __restrict__ mub,
    const float* __restrict__ lvw, const float* __restrict__ lvb,
    float* __restrict__ out)
{
    __shared__ float xr[256];
    __shared__ float h1[512];
    __shared__ float h2[256];
    __shared__ float h3[128];

    const int t = threadIdx.x;
    const int b = blockIdx.x;

    xr[t] = xseq[b * (200 * 256) + t];
    __syncthreads();

    {
        float acc0 = b1[t], acc1 = b1[t + 256];
        for (int i = 0; i < 256; ++i) {
            float xv = xr[i];
            acc0 = fmaf(xv, w1[i * 512 + t],       acc0);
            acc1 = fmaf(xv, w1[i * 512 + t + 256], acc1);
        }
        h1[t]       = fmaxf(acc0, 0.0f);
        h1[t + 256] = fmaxf(acc1, 0.0f);
    }
    __syncthreads();

    {
        float acc = b2[t];
        for (int i = 0; i < 512; ++i) acc = fmaf(h1[i], w2[i * 256 + t], acc);
        h2[t] = fmaxf(acc, 0.0f);
    }
    __syncthreads();

    if (t < 128) {
        float acc = b3[t];
        for (int i = 0; i < 256; ++i) acc = fmaf(h2[i], w3[i * 128 + t], acc);
        h3[t] = fmaxf(acc, 0.0f);
    }
    __syncthreads();

    if (t < 16) {
        float mu = mub[t], lv = lvb[t];
        for (int i = 0; i < 128; ++i) {
            float hv = h3[i];
            mu = fmaf(hv, muw[i * 16 + t], mu);
            lv = fmaf(hv, lvw[i * 16 + t], lv);
        }
        out[OFF_MU + b * 16 + t] = mu;
        out[OFF_LV + b * 16 + t] = lv;
        float z0 = mu + __expf(0.5f * lv) * eps[b * 16 + t];
        out[OFF_ZT + b * 3200 + t] = z0;
    }
}

// ---------------------------------------------------------------------------
// ODE integrator v6: TWO WAVES per batch element (block=128, 2 SIMDs/CU).
//   R4 post-mortem: 1 wave cannot hide LDS latency; all-LDS w2 regressed.
//   New split: wave w owns L2 columns [64w,64w+64) -> per-lane w2 slice is
//   128 floats = 64 v2f, register-resident. ZERO LDS traffic for weights.
//   - L1 duplicated per wave into wave-PRIVATE a1s (no cross-wave sync);
//     L2 reads a1 via uniform-address broadcast float4 (conflict-free).
//   - ONE barrier per feval (a2 exchange), double-buffered by compile-time
//     parity so reuse across fevals is race-free with a single barrier.
//   - L3 + LayerNorm replicated in both waves (z stays in registers).
// ---------------------------------------------------------------------------
__global__ __launch_bounds__(128, 1) void ode_kernel(
    const float* __restrict__ tvec,
    const float* __restrict__ ow1, const float* __restrict__ ob1,
    const float* __restrict__ ow2, const float* __restrict__ ob2,
    const float* __restrict__ ow3, const float* __restrict__ ob3,
    const float* __restrict__ lng, const float* __restrict__ lnb,
    float* __restrict__ out)
{
    __shared__ __align__(16) float a1s[2][128];     // per-wave private
    __shared__ __align__(16) float a2p[2][4 * 36];  // dbuf, padded chunks

    const int tid  = threadIdx.x;
    const int wv   = tid >> 6;       // wave id: 0/1
    const int lane = tid & 63;
    const int b    = blockIdx.x;
    const int d    = lane & 15;      // owned z-dim (replicated x4 per wave)
    const int g    = lane >> 4;      // L3 K-chunk group
    const int c    = wv * 64 + lane; // this thread's L2 output column
    const int j0   = lane, j1 = lane + 64;  // L1 columns (dup per wave)

    // ---- register-resident weights via volatile (loaded exactly once) -----
    const volatile float* vw1 = ow1;
    const volatile float* vw2 = ow2;
    const volatile float* vw3 = ow3;

    float w1r0[16], w1r1[16];
#pragma unroll
    for (int k = 0; k < 16; ++k) {
        w1r0[k] = vw1[k * 128 + j0];
        w1r1[k] = vw1[k * 128 + j1];
    }
    v2f w2r[64];                     // w2[:, c] as 64 K-pairs
#pragma unroll
    for (int q = 0; q < 64; ++q) {
        v2f t0 = { vw2[(2 * q) * 128 + c], vw2[(2 * q + 1) * 128 + c] };
        w2r[q] = t0;
    }
    v2f w3r[16];   // K-chunk g (32 wide), stored in bank-staggered read order
#pragma unroll
    for (int qq = 0; qq < 8; ++qq) {
        int qsel = (qq + 2 * g) & 7;
        int k0   = 32 * g + 4 * qsel;
        v2f t0 = { vw3[(k0 + 0) * 16 + d], vw3[(k0 + 1) * 16 + d] };
        v2f t1 = { vw3[(k0 + 2) * 16 + d], vw3[(k0 + 3) * 16 + d] };
        w3r[2 * qq]     = t0;
        w3r[2 * qq + 1] = t1;
    }
    const volatile float* vb1 = ob1;
    const volatile float* vb2 = ob2;
    const volatile float* vb3 = ob3;
    const volatile float* vlg = lng;
    const volatile float* vlb = lnb;
    const float b1j0 = vb1[j0], b1j1 = vb1[j1];
    const float b2c  = vb2[c];
    const float b3d  = vb3[d];
    const float lngd = vlg[d], lnbd = vlb[d];

    float* ztraj = out + OFF_ZT + b * 3200;   // [200][16]
    float* zdiff = out + OFF_ZD + b * 3184;   // [199][16]

    float z = ztraj[d];                       // z0, replicated x4, both waves

    // one evaluation of f(za); za = zarg[d] per lane (replicated x4).
    // p = compile-time parity selecting the a2p buffer.
    auto feval = [&](float za, int p) -> float {
        // L1 (duplicated per wave): full a1 into wave-private a1s[wv].
        float a0e = 0.0f, a0o = 0.0f, a1e = 0.0f, a1o = 0.0f;
#pragma unroll
        for (int k = 0; k < 16; k += 2) {
            float zk0 = readlane_f(za, k);
            float zk1 = readlane_f(za, k + 1);
            a0e = fmaf(zk0, w1r0[k],     a0e);
            a1e = fmaf(zk0, w1r1[k],     a1e);
            a0o = fmaf(zk1, w1r0[k + 1], a0o);
            a1o = fmaf(zk1, w1r1[k + 1], a1o);
        }
        a1s[wv][j0] = silu_f(a0e + a0o + b1j0);
        a1s[wv][j1] = silu_f(a1e + a1o + b1j1);
        // intra-wave write->read: compiler inserts lgkmcnt, no barrier needed

        // L2: 1 col/lane, K=128 as 64 register v2f pairs; a1 operands via
        // uniform-address broadcast float4 reads (conflict-free).
        v2f A0 = {0.0f, 0.0f}, A1 = {0.0f, 0.0f};
        v2f A2 = {0.0f, 0.0f}, A3 = {0.0f, 0.0f};
        const float4* a14 = (const float4*)a1s[wv];
#pragma unroll
        for (int q4 = 0; q4 < 32; q4 += 2) {
            float4 av0 = a14[q4];
            float4 av1 = a14[q4 + 1];
            A0 = fma2((v2f){ av0.x, av0.y }, w2r[2 * q4],     A0);
            A1 = fma2((v2f){ av0.z, av0.w }, w2r[2 * q4 + 1], A1);
            A2 = fma2((v2f){ av1.x, av1.y }, w2r[2 * q4 + 2], A2);
            A3 = fma2((v2f){ av1.z, av1.w }, w2r[2 * q4 + 3], A3);
        }
        float a2c = silu_f(A0.x + A0.y + A1.x + A1.y
                         + A2.x + A2.y + A3.x + A3.y + b2c);
        a2p[p][(c >> 5) * 36 + (c & 31)] = a2c;
        __syncthreads();                     // the ONE cross-wave barrier

        // L3 (replicated in both waves): output d, K-chunk g (32 wide),
        // bank-staggered b128 reads from the padded a2 buffer.
        v2f pp = {0.0f, 0.0f};
#pragma unroll
        for (int qq = 0; qq < 8; ++qq) {
            int qsel = (qq + 2 * g) & 7;
            float4 av = *(const float4*)&a2p[p][g * 36 + 4 * qsel];
            pp = fma2((v2f){ av.x, av.y }, w3r[2 * qq],     pp);
            pp = fma2((v2f){ av.z, av.w }, w3r[2 * qq + 1], pp);
        }
        // combine 4 K-chunks across lane groups (xor16 then xor32)
        float pd = pp.x + pp.y;
        pd += __shfl_xor(pd, 16);
        pd += __shfl_xor(pd, 32);
        float dz = pd + b3d;

        // LayerNorm over d=0..15 via DPP row sums (replicated result)
        float m  = sum16_dpp(dz) * 0.0625f;
        float df = dz - m;
        float v  = sum16_dpp(df * df) * 0.0625f;
        return df * rsqrtf(v + 1e-5f) * lngd + lnbd;
    };

    for (int l = 0; l < 199; ++l) {
        const float dt = tvec[l + 1] - tvec[l];
        const float h  = dt * 0.125f;          // dt / K, K=8 (exact)
        const float zstart = z;
        for (int s = 0; s < 8; ++s) {
            // 6 fevals per substep: parities 0,1,0,1,0,1 (even count => the
            // next substep starts at 0 again; consecutive fevals always
            // alternate buffers, making one barrier per feval race-free).
            float k1 = feval(z, 0);
            float k2 = feval(z + h * (k1 * (float)(1.0 / 5.0)), 1);
            float k3 = feval(z + h * ((float)(3.0 / 40.0) * k1 + (float)(9.0 / 40.0) * k2), 0);
            float k4 = feval(z + h * ((float)(44.0 / 45.0) * k1 - (float)(56.0 / 15.0) * k2
                                    + (float)(32.0 / 9.0) * k3), 1);
            float k5 = feval(z + h * ((float)(19372.0 / 6561.0) * k1 - (float)(25360.0 / 2187.0) * k2
                                    + (float)(64448.0 / 6561.0) * k3 - (float)(212.0 / 729.0) * k4), 0);
            float k6 = feval(z + h * ((float)(9017.0 / 3168.0) * k1 - (float)(355.0 / 33.0) * k2
                                    + (float)(46732.0 / 5247.0) * k3 + (float)(49.0 / 176.0) * k4
                                    - (float)(5103.0 / 18656.0) * k5), 1);
            z = z + h * ((float)(35.0 / 384.0) * k1 + (float)(500.0 / 1113.0) * k3
                       + (float)(125.0 / 192.0) * k4 - (float)(2187.0 / 6784.0) * k5
                       + (float)(11.0 / 84.0) * k6);
        }
        if (tid < 16) {
            ztraj[(l + 1) * 16 + tid] = z;
            zdiff[l * 16 + tid] = (z - zstart) / dt;
        }
    }
}

// ---------------------------------------------------------------------------
// Decoder: fused 3-layer MLP over 51200 rows. M-tile=16, 256 threads,
// 4 blocks/CU to hide the L2-bound w2 reads. (unchanged from R4)
// ---------------------------------------------------------------------------
#define GS 516   // padded LDS stride for the 16x512 activation tile

__global__ __launch_bounds__(256, 4) void dec_kernel(
    const float* __restrict__ ztr,
    const float* __restrict__ w1, const float* __restrict__ b1,
    const float* __restrict__ w2, const float* __restrict__ b2,
    const float* __restrict__ w3, const float* __restrict__ b3,
    float* __restrict__ xhat)
{
    __shared__ __align__(16) float zt[16 * 17];
    __shared__ __align__(16) float g[16 * GS];

    const int t    = threadIdx.x;
    const int blk  = blockIdx.x;
    const int tr   = t >> 5;
    const int tc   = t & 31;
    const int row0 = blk * 16;
    const int r0   = 2 * tr;

    {
        int r = t >> 4, dd = t & 15;
        zt[r * 17 + dd] = ztr[(row0 + r) * 16 + dd];
    }
    __syncthreads();

    // Phase A: g1 = relu(z @ w1 + b1), K=16
    {
        float acc[2][16];
#pragma unroll
        for (int p = 0; p < 2; ++p)
#pragma unroll
            for (int i = 0; i < 16; ++i) acc[p][i] = 0.0f;

#pragma unroll
        for (int k = 0; k < 16; ++k) {
            float a0 = zt[(r0 + 0) * 17 + k];
            float a1 = zt[(r0 + 1) * 17 + k];
            const float4* wr = (const float4*)(w1 + k * 512 + 16 * tc);
#pragma unroll
            for (int u = 0; u < 4; ++u) {
                float4 wv = wr[u];
                acc[0][4 * u + 0] = fmaf(a0, wv.x, acc[0][4 * u + 0]);
                acc[0][4 * u + 1] = fmaf(a0, wv.y, acc[0][4 * u + 1]);
                acc[0][4 * u + 2] = fmaf(a0, wv.z, acc[0][4 * u + 2]);
                acc[0][4 * u + 3] = fmaf(a0, wv.w, acc[0][4 * u + 3]);
                acc[1][4 * u + 0] = fmaf(a1, wv.x, acc[1][4 * u + 0]);
                acc[1][4 * u + 1] = fmaf(a1, wv.y, acc[1][4 * u + 1]);
                acc[1][4 * u + 2] = fmaf(a1, wv.z, acc[1][4 * u + 2]);
                acc[1][4 * u + 3] = fmaf(a1, wv.w, acc[1][4 * u + 3]);
            }
        }
        const float4* bb = (const float4*)(b1 + 16 * tc);
#pragma unroll
        for (int u = 0; u < 4; ++u) {
            float4 bv = bb[u];
#pragma unroll
            for (int p = 0; p < 2; ++p) {
                g[(r0 + p) * GS + 16 * tc + 4 * u + 0] = fmaxf(acc[p][4 * u + 0] + bv.x, 0.0f);
                g[(r0 + p) * GS + 16 * tc + 4 * u + 1] = fmaxf(acc[p][4 * u + 1] + bv.y, 0.0f);
                g[(r0 + p) * GS + 16 * tc + 4 * u + 2] = fmaxf(acc[p][4 * u + 2] + bv.z, 0.0f);
                g[(r0 + p) * GS + 16 * tc + 4 * u + 3] = fmaxf(acc[p][4 * u + 3] + bv.w, 0.0f);
            }
        }
    }
    __syncthreads();

    // Phase B: g2 = relu(g1 @ w2 + b2), K=512
    {
        float accB[2][16];
#pragma unroll
        for (int p = 0; p < 2; ++p)
#pragma unroll
            for (int i = 0; i < 16; ++i) accB[p][i] = 0.0f;

        for (int k4 = 0; k4 < 128; ++k4) {
            float4 av0 = *(const float4*)&g[(r0 + 0) * GS + 4 * k4];
            float4 av1 = *(const float4*)&g[(r0 + 1) * GS + 4 * k4];
            float a0[4] = {av0.x, av0.y, av0.z, av0.w};
            float a1[4] = {av1.x, av1.y, av1.z, av1.w};
#pragma unroll
            for (int u = 0; u < 4; ++u) {
                const float4* wr = (const float4*)(w2 + (4 * k4 + u) * 512 + 16 * tc);
#pragma unroll
                for (int q = 0; q < 4; ++q) {
                    float4 wv = wr[q];
                    accB[0][4 * q + 0] = fmaf(a0[u], wv.x, accB[0][4 * q + 0]);
                    accB[0][4 * q + 1] = fmaf(a0[u], wv.y, accB[0][4 * q + 1]);
                    accB[0][4 * q + 2] = fmaf(a0[u], wv.z, accB[0][4 * q + 2]);
                    accB[0][4 * q + 3] = fmaf(a0[u], wv.w, accB[0][4 * q + 3]);
                    accB[1][4 * q + 0] = fmaf(a1[u], wv.x, accB[1][4 * q + 0]);
                    accB[1][4 * q + 1] = fmaf(a1[u], wv.y, accB[1][4 * q + 1]);
                    accB[1][4 * q + 2] = fmaf(a1[u], wv.z, accB[1][4 * q + 2]);
                    accB[1][4 * q + 3] = fmaf(a1[u], wv.w, accB[1][4 * q + 3]);
                }
            }
        }
        __syncthreads();
        const float4* bb = (const float4*)(b2 + 16 * tc);
#pragma unroll
        for (int u = 0; u < 4; ++u) {
            float4 bv = bb[u];
#pragma unroll
            for (int p = 0; p < 2; ++p) {
                g[(r0 + p) * GS + 16 * tc + 4 * u + 0] = fmaxf(accB[p][4 * u + 0] + bv.x, 0.0f);
                g[(r0 + p) * GS + 16 * tc + 4 * u + 1] = fmaxf(accB[p][4 * u + 1] + bv.y, 0.0f);
                g[(r0 + p) * GS + 16 * tc + 4 * u + 2] = fmaxf(accB[p][4 * u + 2] + bv.z, 0.0f);
                g[(r0 + p) * GS + 16 * tc + 4 * u + 3] = fmaxf(accB[p][4 * u + 3] + bv.w, 0.0f);
            }
        }
    }
    __syncthreads();

    // Phase C: xhat = g2 @ w3 + b3, N=256 (8 cols/thread), K=512
    {
        float accC[2][8];
#pragma unroll
        for (int p = 0; p < 2; ++p)
#pragma unroll
            for (int i = 0; i < 8; ++i) accC[p][i] = 0.0f;

        for (int k4 = 0; k4 < 128; ++k4) {
            float4 av0 = *(const float4*)&g[(r0 + 0) * GS + 4 * k4];
            float4 av1 = *(const float4*)&g[(r0 + 1) * GS + 4 * k4];
            float a0[4] = {av0.x, av0.y, av0.z, av0.w};
            float a1[4] = {av1.x, av1.y, av1.z, av1.w};
#pragma unroll
            for (int u = 0; u < 4; ++u) {
                const float4* wr = (const float4*)(w3 + (4 * k4 + u) * 256 + 8 * tc);
                float4 w0 = wr[0], w1v = wr[1];
                accC[0][0] = fmaf(a0[u], w0.x,  accC[0][0]);
                accC[0][1] = fmaf(a0[u], w0.y,  accC[0][1]);
                accC[0][2] = fmaf(a0[u], w0.z,  accC[0][2]);
                accC[0][3] = fmaf(a0[u], w0.w,  accC[0][3]);
                accC[0][4] = fmaf(a0[u], w1v.x, accC[0][4]);
                accC[0][5] = fmaf(a0[u], w1v.y, accC[0][5]);
                accC[0][6] = fmaf(a0[u], w1v.z, accC[0][6]);
                accC[0][7] = fmaf(a0[u], w1v.w, accC[0][7]);
                accC[1][0] = fmaf(a1[u], w0.x,  accC[1][0]);
                accC[1][1] = fmaf(a1[u], w0.y,  accC[1][1]);
                accC[1][2] = fmaf(a1[u], w0.z,  accC[1][2]);
                accC[1][3] = fmaf(a1[u], w0.w,  accC[1][3]);
                accC[1][4] = fmaf(a1[u], w1v.x, accC[1][4]);
                accC[1][5] = fmaf(a1[u], w1v.y, accC[1][5]);
                accC[1][6] = fmaf(a1[u], w1v.z, accC[1][6]);
                accC[1][7] = fmaf(a1[u], w1v.w, accC[1][7]);
            }
        }
        const float4* bb = (const float4*)(b3 + 8 * tc);
        float4 bv0 = bb[0], bv1 = bb[1];
#pragma unroll
        for (int p = 0; p < 2; ++p) {
            float4 o0 = make_float4(accC[p][0] + bv0.x, accC[p][1] + bv0.y,
                                    accC[p][2] + bv0.z, accC[p][3] + bv0.w);
            float4 o1 = make_float4(accC[p][4] + bv1.x, accC[p][5] + bv1.y,
                                    accC[p][6] + bv1.z, accC[p][7] + bv1.w);
            float* dst = xhat + (size_t)(row0 + r0 + p) * 256 + 8 * tc;
            *(float4*)(dst)     = o0;
            *(float4*)(dst + 4) = o1;
        }
    }
}

extern "C" void kernel_launch(void* const* d_in, const int* in_sizes, int n_in,
                              void* d_out, int out_size, void* d_ws, size_t ws_size,
                              hipStream_t stream) {
    const float* x_seq  = (const float*)d_in[0];
    const float* tvec   = (const float*)d_in[1];
    const float* eps    = (const float*)d_in[2];
    const float* enc_w1 = (const float*)d_in[3];
    const float* enc_b1 = (const float*)d_in[4];
    const float* enc_w2 = (const float*)d_in[5];
    const float* enc_b2 = (const float*)d_in[6];
    const float* enc_w3 = (const float*)d_in[7];
    const float* enc_b3 = (const float*)d_in[8];
    const float* mu_w   = (const float*)d_in[9];
    const float* mu_b   = (const float*)d_in[10];
    const float* lv_w   = (const float*)d_in[11];
    const float* lv_b   = (const float*)d_in[12];
    const float* ode_w1 = (const float*)d_in[13];
    const float* ode_b1 = (const float*)d_in[14];
    const float* ode_w2 = (const float*)d_in[15];
    const float* ode_b2 = (const float*)d_in[16];
    const float* ode_w3 = (const float*)d_in[17];
    const float* ode_b3 = (const float*)d_in[18];
    const float* ln_g   = (const float*)d_in[19];
    const float* ln_b   = (const float*)d_in[20];
    const float* dec_w1 = (const float*)d_in[21];
    const float* dec_b1 = (const float*)d_in[22];
    const float* dec_w2 = (const float*)d_in[23];
    const float* dec_b2 = (const float*)d_in[24];
    const float* dec_w3 = (const float*)d_in[25];
    const float* dec_b3 = (const float*)d_in[26];
    float* out = (float*)d_out;

    enc_kernel<<<256, 256, 0, stream>>>(x_seq, eps, enc_w1, enc_b1, enc_w2, enc_b2,
                                        enc_w3, enc_b3, mu_w, mu_b, lv_w, lv_b, out);
    ode_kernel<<<256, 128, 0, stream>>>(tvec, ode_w1, ode_b1, ode_w2, ode_b2,
                                        ode_w3, ode_b3, ln_g, ln_b, out);
    dec_kernel<<<3200, 256, 0, stream>>>(out + OFF_ZT, dec_w1, dec_b1, dec_w2, dec_b2,
                                         dec_w3, dec_b3, out);
}

// Round 7
// 10699.443 us; speedup vs baseline: 1.5333x; 1.0010x over previous
//
#include <hip/hip_runtime.h>

// Output layout (flat f32, reference return order):
//   xhat  : B*L*N   = 13,107,200  @ 0
//   mu    : B*D     =      4,096  @ 13,107,200
//   logvar: B*D     =      4,096  @ 13,111,296
//   z_traj: B*L*D   =    819,200  @ 13,115,392
//   zdiff : B*(L-1)*D =  815,104  @ 13,934,592
#define OFF_MU   13107200
#define OFF_LV   13111296
#define OFF_ZT   13115392
#define OFF_ZD   13934592

typedef float v2f __attribute__((ext_vector_type(2)));

__device__ __forceinline__ float silu_f(float x) {
    return x / (1.0f + __expf(-x));
}

__device__ __forceinline__ float readlane_f(float v, int l) {
    return __uint_as_float(__builtin_amdgcn_readlane(__float_as_uint(v), l));
}

__device__ __forceinline__ v2f fma2(v2f a, v2f b, v2f c) {
    return __builtin_elementwise_fma(a, b, c);
}

// x + dpp_move(x) with compile-time DPP control. VALU-latency cross-lane.
template <int CTRL>
__device__ __forceinline__ float dppadd(float x) {
    int y = __builtin_amdgcn_update_dpp(0, __float_as_int(x), CTRL, 0xF, 0xF, true);
    return x + __int_as_float(y);
}

// Sum of x over each 16-lane row (values replicated per row afterwards).
__device__ __forceinline__ float sum16_dpp(float x) {
    x = dppadd<0xB1>(x);    // quad_perm xor1
    x = dppadd<0x4E>(x);    // quad_perm xor2
    x = dppadd<0x141>(x);   // row_half_mirror (xor4 once quad-uniform)
    x = dppadd<0x140>(x);   // row_mirror (xor8 once 8-uniform)
    return x;
}

// ---------------------------------------------------------------------------
// Encoder: one block per batch row. x0(256) -> 512 -> 256 -> 128 -> mu/lv(16)
// (unchanged — negligible cost)
// ---------------------------------------------------------------------------
__global__ __launch_bounds__(256) void enc_kernel(
    const float* __restrict__ xseq, const float* __restrict__ eps,
    const float* __restrict__ w1, const float* __restrict__ b1,
    const float* __restrict__ w2, const float* __restrict__ b2,
    const float* __restrict__ w3, const float* __restrict__ b3,
    const float* __restrict__ muw, const float* __restrict__ mub,
    const float* __restrict__ lvw, const float* __restrict__ lvb,
    float* __restrict__ out)
{
    __shared__ float xr[256];
    __shared__ float h1[512];
    __shared__ float h2[256];
    __shared__ float h3[128];

    const int t = threadIdx.x;
    const int b = blockIdx.x;

    xr[t] = xseq[b * (200 * 256) + t];
    __syncthreads();

    {
        float acc0 = b1[t], acc1 = b1[t + 256];
        for (int i = 0; i < 256; ++i) {
            float xv = xr[i];
            acc0 = fmaf(xv, w1[i * 512 + t],       acc0);
            acc1 = fmaf(xv, w1[i * 512 + t + 256], acc1);
        }
        h1[t]       = fmaxf(acc0, 0.0f);
        h1[t + 256] = fmaxf(acc1, 0.0f);
    }
    __syncthreads();

    {
        float acc = b2[t];
        for (int i = 0; i < 512; ++i) acc = fmaf(h1[i], w2[i * 256 + t], acc);
        h2[t] = fmaxf(acc, 0.0f);
    }
    __syncthreads();

    if (t < 128) {
        float acc = b3[t];
        for (int i = 0; i < 256; ++i) acc = fmaf(h2[i], w3[i * 128 + t], acc);
        h3[t] = fmaxf(acc, 0.0f);
    }
    __syncthreads();

    if (t < 16) {
        float mu = mub[t], lv = lvb[t];
        for (int i = 0; i < 128; ++i) {
            float hv = h3[i];
            mu = fmaf(hv, muw[i * 16 + t], mu);
            lv = fmaf(hv, lvw[i * 16 + t], lv);
        }
        out[OFF_MU + b * 16 + t] = mu;
        out[OFF_LV + b * 16 + t] = lv;
        float z0 = mu + __expf(0.5f * lv) * eps[b * 16 + t];
        out[OFF_ZT + b * 3200 + t] = z0;
    }
}

// ---------------------------------------------------------------------------
// ODE integrator v7: TWO WAVES per batch element (block=128, 2 SIMDs/CU).
//   R5 post-mortem: allocator capped arch VGPRs at ~124 (occupancy heuristic)
//   and parked ~100 weight floats in AGPRs -> v_accvgpr copies on every use.
//   Fix: amdgpu_waves_per_eu(1,1) pins occupancy target to 1 wave/EU ->
//   full 512-reg budget, weights become true VGPRs.
//   Also: one-pass LayerNorm (Σdz and Σdz² as parallel DPP chains).
// ---------------------------------------------------------------------------
__global__ __launch_bounds__(128)
__attribute__((amdgpu_waves_per_eu(1, 1)))
void ode_kernel(
    const float* __restrict__ tvec,
    const float* __restrict__ ow1, const float* __restrict__ ob1,
    const float* __restrict__ ow2, const float* __restrict__ ob2,
    const float* __restrict__ ow3, const float* __restrict__ ob3,
    const float* __restrict__ lng, const float* __restrict__ lnb,
    float* __restrict__ out)
{
    __shared__ __align__(16) float a1s[2][128];     // per-wave private
    __shared__ __align__(16) float a2p[2][4 * 36];  // dbuf, padded chunks

    const int tid  = threadIdx.x;
    const int wv   = tid >> 6;       // wave id: 0/1
    const int lane = tid & 63;
    const int b    = blockIdx.x;
    const int d    = lane & 15;      // owned z-dim (replicated x4 per wave)
    const int g    = lane >> 4;      // L3 K-chunk group
    const int c    = wv * 64 + lane; // this thread's L2 output column
    const int j0   = lane, j1 = lane + 64;  // L1 columns (dup per wave)

    // ---- register-resident weights via volatile (loaded exactly once) -----
    const volatile float* vw1 = ow1;
    const volatile float* vw2 = ow2;
    const volatile float* vw3 = ow3;

    float w1r0[16], w1r1[16];
#pragma unroll
    for (int k = 0; k < 16; ++k) {
        w1r0[k] = vw1[k * 128 + j0];
        w1r1[k] = vw1[k * 128 + j1];
    }
    v2f w2r[64];                     // w2[:, c] as 64 K-pairs
#pragma unroll
    for (int q = 0; q < 64; ++q) {
        v2f t0 = { vw2[(2 * q) * 128 + c], vw2[(2 * q + 1) * 128 + c] };
        w2r[q] = t0;
    }
    v2f w3r[16];   // K-chunk g (32 wide), stored in bank-staggered read order
#pragma unroll
    for (int qq = 0; qq < 8; ++qq) {
        int qsel = (qq + 2 * g) & 7;
        int k0   = 32 * g + 4 * qsel;
        v2f t0 = { vw3[(k0 + 0) * 16 + d], vw3[(k0 + 1) * 16 + d] };
        v2f t1 = { vw3[(k0 + 2) * 16 + d], vw3[(k0 + 3) * 16 + d] };
        w3r[2 * qq]     = t0;
        w3r[2 * qq + 1] = t1;
    }
    const volatile float* vb1 = ob1;
    const volatile float* vb2 = ob2;
    const volatile float* vb3 = ob3;
    const volatile float* vlg = lng;
    const volatile float* vlb = lnb;
    const float b1j0 = vb1[j0], b1j1 = vb1[j1];
    const float b2c  = vb2[c];
    const float b3d  = vb3[d];
    const float lngd = vlg[d], lnbd = vlb[d];

    float* ztraj = out + OFF_ZT + b * 3200;   // [200][16]
    float* zdiff = out + OFF_ZD + b * 3184;   // [199][16]

    float z = ztraj[d];                       // z0, replicated x4, both waves

    // one evaluation of f(za); za = zarg[d] per lane (replicated x4).
    // p = compile-time parity selecting the a2p buffer.
    auto feval = [&](float za, int p) -> float {
        // L1 (duplicated per wave): full a1 into wave-private a1s[wv].
        float a0e = 0.0f, a0o = 0.0f, a1e = 0.0f, a1o = 0.0f;
#pragma unroll
        for (int k = 0; k < 16; k += 2) {
            float zk0 = readlane_f(za, k);
            float zk1 = readlane_f(za, k + 1);
            a0e = fmaf(zk0, w1r0[k],     a0e);
            a1e = fmaf(zk0, w1r1[k],     a1e);
            a0o = fmaf(zk1, w1r0[k + 1], a0o);
            a1o = fmaf(zk1, w1r1[k + 1], a1o);
        }
        a1s[wv][j0] = silu_f(a0e + a0o + b1j0);
        a1s[wv][j1] = silu_f(a1e + a1o + b1j1);
        // intra-wave write->read: compiler inserts lgkmcnt, no barrier needed

        // L2: 1 col/lane, K=128 as 64 register v2f pairs; a1 operands via
        // uniform-address broadcast float4 reads (conflict-free).
        v2f A0 = {0.0f, 0.0f}, A1 = {0.0f, 0.0f};
        v2f A2 = {0.0f, 0.0f}, A3 = {0.0f, 0.0f};
        const float4* a14 = (const float4*)a1s[wv];
#pragma unroll
        for (int q4 = 0; q4 < 32; q4 += 2) {
            float4 av0 = a14[q4];
            float4 av1 = a14[q4 + 1];
            A0 = fma2((v2f){ av0.x, av0.y }, w2r[2 * q4],     A0);
            A1 = fma2((v2f){ av0.z, av0.w }, w2r[2 * q4 + 1], A1);
            A2 = fma2((v2f){ av1.x, av1.y }, w2r[2 * q4 + 2], A2);
            A3 = fma2((v2f){ av1.z, av1.w }, w2r[2 * q4 + 3], A3);
        }
        float a2c = silu_f(A0.x + A0.y + A1.x + A1.y
                         + A2.x + A2.y + A3.x + A3.y + b2c);
        a2p[p][(c >> 5) * 36 + (c & 31)] = a2c;
        __syncthreads();                     // the ONE cross-wave barrier

        // L3 (replicated in both waves): output d, K-chunk g (32 wide),
        // broadcast b128 reads from the padded a2 buffer.
        v2f pp = {0.0f, 0.0f};
#pragma unroll
        for (int qq = 0; qq < 8; ++qq) {
            int qsel = (qq + 2 * g) & 7;
            float4 av = *(const float4*)&a2p[p][g * 36 + 4 * qsel];
            pp = fma2((v2f){ av.x, av.y }, w3r[2 * qq],     pp);
            pp = fma2((v2f){ av.z, av.w }, w3r[2 * qq + 1], pp);
        }
        // combine 4 K-chunks across lane groups (xor16 then xor32)
        float pd = pp.x + pp.y;
        pd += __shfl_xor(pd, 16);
        pd += __shfl_xor(pd, 32);
        float dz = pd + b3d;

        // One-pass LayerNorm over d=0..15: Σdz and Σdz² are independent DPP
        // chains (interleave); var = E[dz²] − m².
        float s1 = sum16_dpp(dz);
        float s2 = sum16_dpp(dz * dz);
        float m  = s1 * 0.0625f;
        float v  = fmaf(m, -m, s2 * 0.0625f);
        return (dz - m) * rsqrtf(v + 1e-5f) * lngd + lnbd;
    };

    for (int l = 0; l < 199; ++l) {
        const float dt = tvec[l + 1] - tvec[l];
        const float h  = dt * 0.125f;          // dt / K, K=8 (exact)
        const float zstart = z;
        for (int s = 0; s < 8; ++s) {
            // 6 fevals per substep: parities 0,1,0,1,0,1 (even count => the
            // next substep starts at 0 again; consecutive fevals always
            // alternate buffers, making one barrier per feval race-free).
            float k1 = feval(z, 0);
            float k2 = feval(z + h * (k1 * (float)(1.0 / 5.0)), 1);
            float k3 = feval(z + h * ((float)(3.0 / 40.0) * k1 + (float)(9.0 / 40.0) * k2), 0);
            float k4 = feval(z + h * ((float)(44.0 / 45.0) * k1 - (float)(56.0 / 15.0) * k2
                                    + (float)(32.0 / 9.0) * k3), 1);
            float k5 = feval(z + h * ((float)(19372.0 / 6561.0) * k1 - (float)(25360.0 / 2187.0) * k2
                                    + (float)(64448.0 / 6561.0) * k3 - (float)(212.0 / 729.0) * k4), 0);
            float k6 = feval(z + h * ((float)(9017.0 / 3168.0) * k1 - (float)(355.0 / 33.0) * k2
                                    + (float)(46732.0 / 5247.0) * k3 + (float)(49.0 / 176.0) * k4
                                    - (float)(5103.0 / 18656.0) * k5), 1);
            z = z + h * ((float)(35.0 / 384.0) * k1 + (float)(500.0 / 1113.0) * k3
                       + (float)(125.0 / 192.0) * k4 - (float)(2187.0 / 6784.0) * k5
                       + (float)(11.0 / 84.0) * k6);
        }
        if (tid < 16) {
            ztraj[(l + 1) * 16 + tid] = z;
            zdiff[l * 16 + tid] = (z - zstart) / dt;
        }
    }
}

// ---------------------------------------------------------------------------
// Decoder: fused 3-layer MLP over 51200 rows. M-tile=16, 256 threads,
// 4 blocks/CU to hide the L2-bound w2 reads. (unchanged)
// ---------------------------------------------------------------------------
#define GS 516   // padded LDS stride for the 16x512 activation tile

__global__ __launch_bounds__(256, 4) void dec_kernel(
    const float* __restrict__ ztr,
    const float* __restrict__ w1, const float* __restrict__ b1,
    const float* __restrict__ w2, const float* __restrict__ b2,
    const float* __restrict__ w3, const float* __restrict__ b3,
    float* __restrict__ xhat)
{
    __shared__ __align__(16) float zt[16 * 17];
    __shared__ __align__(16) float g[16 * GS];

    const int t    = threadIdx.x;
    const int blk  = blockIdx.x;
    const int tr   = t >> 5;
    const int tc   = t & 31;
    const int row0 = blk * 16;
    const int r0   = 2 * tr;

    {
        int r = t >> 4, dd = t & 15;
        zt[r * 17 + dd] = ztr[(row0 + r) * 16 + dd];
    }
    __syncthreads();

    // Phase A: g1 = relu(z @ w1 + b1), K=16
    {
        float acc[2][16];
#pragma unroll
        for (int p = 0; p < 2; ++p)
#pragma unroll
            for (int i = 0; i < 16; ++i) acc[p][i] = 0.0f;

#pragma unroll
        for (int k = 0; k < 16; ++k) {
            float a0 = zt[(r0 + 0) * 17 + k];
            float a1 = zt[(r0 + 1) * 17 + k];
            const float4* wr = (const float4*)(w1 + k * 512 + 16 * tc);
#pragma unroll
            for (int u = 0; u < 4; ++u) {
                float4 wv = wr[u];
                acc[0][4 * u + 0] = fmaf(a0, wv.x, acc[0][4 * u + 0]);
                acc[0][4 * u + 1] = fmaf(a0, wv.y, acc[0][4 * u + 1]);
                acc[0][4 * u + 2] = fmaf(a0, wv.z, acc[0][4 * u + 2]);
                acc[0][4 * u + 3] = fmaf(a0, wv.w, acc[0][4 * u + 3]);
                acc[1][4 * u + 0] = fmaf(a1, wv.x, acc[1][4 * u + 0]);
                acc[1][4 * u + 1] = fmaf(a1, wv.y, acc[1][4 * u + 1]);
                acc[1][4 * u + 2] = fmaf(a1, wv.z, acc[1][4 * u + 2]);
                acc[1][4 * u + 3] = fmaf(a1, wv.w, acc[1][4 * u + 3]);
            }
        }
        const float4* bb = (const float4*)(b1 + 16 * tc);
#pragma unroll
        for (int u = 0; u < 4; ++u) {
            float4 bv = bb[u];
#pragma unroll
            for (int p = 0; p < 2; ++p) {
                g[(r0 + p) * GS + 16 * tc + 4 * u + 0] = fmaxf(acc[p][4 * u + 0] + bv.x, 0.0f);
                g[(r0 + p) * GS + 16 * tc + 4 * u + 1] = fmaxf(acc[p][4 * u + 1] + bv.y, 0.0f);
                g[(r0 + p) * GS + 16 * tc + 4 * u + 2] = fmaxf(acc[p][4 * u + 2] + bv.z, 0.0f);
                g[(r0 + p) * GS + 16 * tc + 4 * u + 3] = fmaxf(acc[p][4 * u + 3] + bv.w, 0.0f);
            }
        }
    }
    __syncthreads();

    // Phase B: g2 = relu(g1 @ w2 + b2), K=512
    {
        float accB[2][16];
#pragma unroll
        for (int p = 0; p < 2; ++p)
#pragma unroll
            for (int i = 0; i < 16; ++i) accB[p][i] = 0.0f;

        for (int k4 = 0; k4 < 128; ++k4) {
            float4 av0 = *(const float4*)&g[(r0 + 0) * GS + 4 * k4];
            float4 av1 = *(const float4*)&g[(r0 + 1) * GS + 4 * k4];
            float a0[4] = {av0.x, av0.y, av0.z, av0.w};
            float a1[4] = {av1.x, av1.y, av1.z, av1.w};
#pragma unroll
            for (int u = 0; u < 4; ++u) {
                const float4* wr = (const float4*)(w2 + (4 * k4 + u) * 512 + 16 * tc);
#pragma unroll
                for (int q = 0; q < 4; ++q) {
                    float4 wv = wr[q];
                    accB[0][4 * q + 0] = fmaf(a0[u], wv.x, accB[0][4 * q + 0]);
                    accB[0][4 * q + 1] = fmaf(a0[u], wv.y, accB[0][4 * q + 1]);
                    accB[0][4 * q + 2] = fmaf(a0[u], wv.z, accB[0][4 * q + 2]);
                    accB[0][4 * q + 3] = fmaf(a0[u], wv.w, accB[0][4 * q + 3]);
                    accB[1][4 * q + 0] = fmaf(a1[u], wv.x, accB[1][4 * q + 0]);
                    accB[1][4 * q + 1] = fmaf(a1[u], wv.y, accB[1][4 * q + 1]);
                    accB[1][4 * q + 2] = fmaf(a1[u], wv.z, accB[1][4 * q + 2]);
                    accB[1][4 * q + 3] = fmaf(a1[u], wv.w, accB[1][4 * q + 3]);
                }
            }
        }
        __syncthreads();
        const float4* bb = (const float4*)(b2 + 16 * tc);
#pragma unroll
        for (int u = 0; u < 4; ++u) {
            float4 bv = bb[u];
#pragma unroll
            for (int p = 0; p < 2; ++p) {
                g[(r0 + p) * GS + 16 * tc + 4 * u + 0] = fmaxf(accB[p][4 * u + 0] + bv.x, 0.0f);
                g[(r0 + p) * GS + 16 * tc + 4 * u + 1] = fmaxf(accB[p][4 * u + 1] + bv.y, 0.0f);
                g[(r0 + p) * GS + 16 * tc + 4 * u + 2] = fmaxf(accB[p][4 * u + 2] + bv.z, 0.0f);
                g[(r0 + p) * GS + 16 * tc + 4 * u + 3] = fmaxf(accB[p][4 * u + 3] + bv.w, 0.0f);
            }
        }
    }
    __syncthreads();

    // Phase C: xhat = g2 @ w3 + b3, N=256 (8 cols/thread), K=512
    {
        float accC[2][8];
#pragma unroll
        for (int p = 0; p < 2; ++p)
#pragma unroll
            for (int i = 0; i < 8; ++i) accC[p][i] = 0.0f;

        for (int k4 = 0; k4 < 128; ++k4) {
            float4 av0 = *(const float4*)&g[(r0 + 0) * GS + 4 * k4];
            float4 av1 = *(const float4*)&g[(r0 + 1) * GS + 4 * k4];
            float a0[4] = {av0.x, av0.y, av0.z, av0.w};
            float a1[4] = {av1.x, av1.y, av1.z, av1.w};
#pragma unroll
            for (int u = 0; u < 4; ++u) {
                const float4* wr = (const float4*)(w3 + (4 * k4 + u) * 256 + 8 * tc);
                float4 w0 = wr[0], w1v = wr[1];
                accC[0][0] = fmaf(a0[u], w0.x,  accC[0][0]);
                accC[0][1] = fmaf(a0[u], w0.y,  accC[0][1]);
                accC[0][2] = fmaf(a0[u], w0.z,  accC[0][2]);
                accC[0][3] = fmaf(a0[u], w0.w,  accC[0][3]);
                accC[0][4] = fmaf(a0[u], w1v.x, accC[0][4]);
                accC[0][5] = fmaf(a0[u], w1v.y, accC[0][5]);
                accC[0][6] = fmaf(a0[u], w1v.z, accC[0][6]);
                accC[0][7] = fmaf(a0[u], w1v.w, accC[0][7]);
                accC[1][0] = fmaf(a1[u], w0.x,  accC[1][0]);
                accC[1][1] = fmaf(a1[u], w0.y,  accC[1][1]);
                accC[1][2] = fmaf(a1[u], w0.z,  accC[1][2]);
                accC[1][3] = fmaf(a1[u], w0.w,  accC[1][3]);
                accC[1][4] = fmaf(a1[u], w1v.x, accC[1][4]);
                accC[1][5] = fmaf(a1[u], w1v.y, accC[1][5]);
                accC[1][6] = fmaf(a1[u], w1v.z, accC[1][6]);
                accC[1][7] = fmaf(a1[u], w1v.w, accC[1][7]);
            }
        }
        const float4* bb = (const float4*)(b3 + 8 * tc);
        float4 bv0 = bb[0], bv1 = bb[1];
#pragma unroll
        for (int p = 0; p < 2; ++p) {
            float4 o0 = make_float4(accC[p][0] + bv0.x, accC[p][1] + bv0.y,
                                    accC[p][2] + bv0.z, accC[p][3] + bv0.w);
            float4 o1 = make_float4(accC[p][4] + bv1.x, accC[p][5] + bv1.y,
                                    accC[p][6] + bv1.z, accC[p][7] + bv1.w);
            float* dst = xhat + (size_t)(row0 + r0 + p) * 256 + 8 * tc;
            *(float4*)(dst)     = o0;
            *(float4*)(dst + 4) = o1;
        }
    }
}

extern "C" void kernel_launch(void* const* d_in, const int* in_sizes, int n_in,
                              void* d_out, int out_size, void* d_ws, size_t ws_size,
                              hipStream_t stream) {
    const float* x_seq  = (const float*)d_in[0];
    const float* tvec   = (const float*)d_in[1];
    const float* eps    = (const float*)d_in[2];
    const float* enc_w1 = (const float*)d_in[3];
    const float* enc_b1 = (const float*)d_in[4];
    const float* enc_w2 = (const float*)d_in[5];
    const float* enc_b2 = (const float*)d_in[6];
    const float* enc_w3 = (const float*)d_in[7];
    const float* enc_b3 = (const float*)d_in[8];
    const float* mu_w   = (const float*)d_in[9];
    const float* mu_b   = (const float*)d_in[10];
    const float* lv_w   = (const float*)d_in[11];
    const float* lv_b   = (const float*)d_in[12];
    const float* ode_w1 = (const float*)d_in[13];
    const float* ode_b1 = (const float*)d_in[14];
    const float* ode_w2 = (const float*)d_in[15];
    const float* ode_b2 = (const float*)d_in[16];
    const float* ode_w3 = (const float*)d_in[17];
    const float* ode_b3 = (const float*)d_in[18];
    const float* ln_g   = (const float*)d_in[19];
    const float* ln_b   = (const float*)d_in[20];
    const float* dec_w1 = (const float*)d_in[21];
    const float* dec_b1 = (const float*)d_in[22];
    const float* dec_w2 = (const float*)d_in[23];
    const float* dec_b2 = (const float*)d_in[24];
    const float* dec_w3 = (const float*)d_in[25];
    const float* dec_b3 = (const float*)d_in[26];
    float* out = (float*)d_out;

    enc_kernel<<<256, 256, 0, stream>>>(x_seq, eps, enc_w1, enc_b1, enc_w2, enc_b2,
                                        enc_w3, enc_b3, mu_w, mu_b, lv_w, lv_b, out);
    ode_kernel<<<256, 128, 0, stream>>>(tvec, ode_w1, ode_b1, ode_w2, ode_b2,
                                        ode_w3, ode_b3, ln_g, ln_b, out);
    dec_kernel<<<3200, 256, 0, stream>>>(out + OFF_ZT, dec_w1, dec_b1, dec_w2, dec_b2,
                                         dec_w3, dec_b3, out);
}

// Round 8
// 8945.544 us; speedup vs baseline: 1.8340x; 1.1961x over previous
//
#include <hip/hip_runtime.h>

// Output layout (flat f32, reference return order):
//   xhat  : B*L*N   = 13,107,200  @ 0
//   mu    : B*D     =      4,096  @ 13,107,200
//   logvar: B*D     =      4,096  @ 13,111,296
//   z_traj: B*L*D   =    819,200  @ 13,115,392
//   zdiff : B*(L-1)*D =  815,104  @ 13,934,592
#define OFF_MU   13107200
#define OFF_LV   13111296
#define OFF_ZT   13115392
#define OFF_ZD   13934592

typedef float v2f __attribute__((ext_vector_type(2)));

__device__ __forceinline__ float silu_f(float x) {
    return x / (1.0f + __expf(-x));
}

__device__ __forceinline__ float readlane_f(float v, int l) {
    return __uint_as_float(__builtin_amdgcn_readlane(__float_as_uint(v), l));
}

__device__ __forceinline__ v2f fma2(v2f a, v2f b, v2f c) {
    return __builtin_elementwise_fma(a, b, c);
}

// x + dpp_move(x) with compile-time DPP control. VALU-latency cross-lane.
template <int CTRL>
__device__ __forceinline__ float dppadd(float x) {
    int y = __builtin_amdgcn_update_dpp(0, __float_as_int(x), CTRL, 0xF, 0xF, true);
    return x + __int_as_float(y);
}

// Sum of x over each 16-lane row (values replicated per row afterwards).
__device__ __forceinline__ float sum16_dpp(float x) {
    x = dppadd<0xB1>(x);    // quad_perm xor1
    x = dppadd<0x4E>(x);    // quad_perm xor2
    x = dppadd<0x141>(x);   // row_half_mirror (xor4 once quad-uniform)
    x = dppadd<0x140>(x);   // row_mirror (xor8 once 8-uniform)
    return x;
}

// ---------------------------------------------------------------------------
// Encoder: one block per batch row. x0(256) -> 512 -> 256 -> 128 -> mu/lv(16)
// (unchanged — negligible cost)
// ---------------------------------------------------------------------------
__global__ __launch_bounds__(256) void enc_kernel(
    const float* __restrict__ xseq, const float* __restrict__ eps,
    const float* __restrict__ w1, const float* __restrict__ b1,
    const float* __restrict__ w2, const float* __restrict__ b2,
    const float* __restrict__ w3, const float* __restrict__ b3,
    const float* __restrict__ muw, const float* __restrict__ mub,
    const float* __restrict__ lvw, const float* __restrict__ lvb,
    float* __restrict__ out)
{
    __shared__ float xr[256];
    __shared__ float h1[512];
    __shared__ float h2[256];
    __shared__ float h3[128];

    const int t = threadIdx.x;
    const int b = blockIdx.x;

    xr[t] = xseq[b * (200 * 256) + t];
    __syncthreads();

    {
        float acc0 = b1[t], acc1 = b1[t + 256];
        for (int i = 0; i < 256; ++i) {
            float xv = xr[i];
            acc0 = fmaf(xv, w1[i * 512 + t],       acc0);
            acc1 = fmaf(xv, w1[i * 512 + t + 256], acc1);
        }
        h1[t]       = fmaxf(acc0, 0.0f);
        h1[t + 256] = fmaxf(acc1, 0.0f);
    }
    __syncthreads();

    {
        float acc = b2[t];
        for (int i = 0; i < 512; ++i) acc = fmaf(h1[i], w2[i * 256 + t], acc);
        h2[t] = fmaxf(acc, 0.0f);
    }
    __syncthreads();

    if (t < 128) {
        float acc = b3[t];
        for (int i = 0; i < 256; ++i) acc = fmaf(h2[i], w3[i * 128 + t], acc);
        h3[t] = fmaxf(acc, 0.0f);
    }
    __syncthreads();

    if (t < 16) {
        float mu = mub[t], lv = lvb[t];
        for (int i = 0; i < 128; ++i) {
            float hv = h3[i];
            mu = fmaf(hv, muw[i * 16 + t], mu);
            lv = fmaf(hv, lvw[i * 16 + t], lv);
        }
        out[OFF_MU + b * 16 + t] = mu;
        out[OFF_LV + b * 16 + t] = lv;
        float z0 = mu + __expf(0.5f * lv) * eps[b * 16 + t];
        out[OFF_ZT + b * 3200 + t] = z0;
    }
}

// ---------------------------------------------------------------------------
// ODE integrator v8: FOUR WAVES per batch element (block=256, 4 SIMDs/CU).
//   R5/R7 post-mortem: allocator caps arch VGPRs ~132 regardless of
//   attributes; 2-wave layout needs 224 floats/lane -> ~90 in AGPRs ->
//   v_accvgpr copies dominate. Fix: K-split L2 so per-lane weight demand is
//   112 floats (w1 16 + w2 64 + w3 32) — fits under the cap by construction.
//   Wave w: computes a1[32w..32w+32) (wave-private, no sync), then L2
//   partials for ALL 128 cols over K-range [32w,32w+32). Two barriers/feval:
//   part -> combine(+silu) -> a2s -> L3 replicated in all waves.
//   L3 cross-group combine via wave-private LDS (p3s) instead of 2 serial
//   ds_swizzles. One-pass LayerNorm via dual DPP chains.
//   Race audit (single-buffered part/a2s, 2 barriers): writer of feval N+1
//   reaches its write only after passing a barrier that all readers of
//   feval N passed after their reads — safe for both part and a2s.
// ---------------------------------------------------------------------------
__global__ __launch_bounds__(256, 1) void ode_kernel(
    const float* __restrict__ tvec,
    const float* __restrict__ ow1, const float* __restrict__ ob1,
    const float* __restrict__ ow2, const float* __restrict__ ob2,
    const float* __restrict__ ow3, const float* __restrict__ ob3,
    const float* __restrict__ lng, const float* __restrict__ lnb,
    float* __restrict__ out)
{
    __shared__ __align__(16) float a1s[4][32];    // wave-private a1 slices
    __shared__ __align__(16) float part[4 * 128]; // L2 partials [wave][col]
    __shared__ __align__(16) float a2s[128];
    __shared__ __align__(16) float p3s[4 * 64];   // wave-private L3 partials

    const int tid  = threadIdx.x;
    const int wv   = tid >> 6;       // wave id 0..3 = K-quarter
    const int lane = tid & 63;
    const int b    = blockIdx.x;
    const int d    = lane & 15;      // owned z-dim (replicated x4 per wave)
    const int g    = lane >> 4;      // L3 K-chunk group
    const int c0   = lane, c1 = lane + 64;      // L2 output columns
    const int col1 = 32 * wv + (lane & 31);     // L1 column (lanes<32 write)

    // ---- register-resident weights via volatile (loaded exactly once) -----
    const volatile float* vw1 = ow1;
    const volatile float* vw2 = ow2;
    const volatile float* vw3 = ow3;

    float w1r[16];
#pragma unroll
    for (int k = 0; k < 16; ++k) w1r[k] = vw1[k * 128 + col1];

    v2f w2r0[16], w2r1[16];          // K-quarter wv, cols c0/c1, K-pairs
#pragma unroll
    for (int q = 0; q < 16; ++q) {
        int k0 = 32 * wv + 2 * q;
        v2f t0 = { vw2[k0 * 128 + c0], vw2[(k0 + 1) * 128 + c0] };
        v2f t1 = { vw2[k0 * 128 + c1], vw2[(k0 + 1) * 128 + c1] };
        w2r0[q] = t0;
        w2r1[q] = t1;
    }
    v2f w3r[16];   // K-chunk g (32 wide), stored in bank-staggered read order
#pragma unroll
    for (int qq = 0; qq < 8; ++qq) {
        int qsel = (qq + 2 * g) & 7;
        int k0   = 32 * g + 4 * qsel;
        v2f t0 = { vw3[(k0 + 0) * 16 + d], vw3[(k0 + 1) * 16 + d] };
        v2f t1 = { vw3[(k0 + 2) * 16 + d], vw3[(k0 + 3) * 16 + d] };
        w3r[2 * qq]     = t0;
        w3r[2 * qq + 1] = t1;
    }
    const volatile float* vb1 = ob1;
    const volatile float* vb2 = ob2;
    const volatile float* vb3 = ob3;
    const volatile float* vlg = lng;
    const volatile float* vlb = lnb;
    const float b1c  = vb1[col1];
    const float b2t  = vb2[tid & 127];   // used by threads < 128 in combine
    const float b3d  = vb3[d];
    const float lngd = vlg[d], lnbd = vlb[d];

    float* ztraj = out + OFF_ZT + b * 3200;   // [200][16]
    float* zdiff = out + OFF_ZD + b * 3184;   // [199][16]

    float z = ztraj[d];                       // z0, replicated, all waves

    // one evaluation of f(za); za = zarg[d] per lane (replicated x4).
    auto feval = [&](float za) -> float {
        // L1: this wave's 32 a1 columns only. zarg via readlane -> SGPR.
        float ae = 0.0f, ao = 0.0f;
#pragma unroll
        for (int k = 0; k < 16; k += 2) {
            float zk0 = readlane_f(za, k);
            float zk1 = readlane_f(za, k + 1);
            ae = fmaf(zk0, w1r[k],     ae);
            ao = fmaf(zk1, w1r[k + 1], ao);
        }
        if (lane < 32) a1s[wv][lane] = silu_f(ae + ao + b1c);
        // intra-wave write->read: compiler inserts lgkmcnt, no barrier

        // L2 partial: K-range [32wv,32wv+32), 2 cols/lane.
        // a1 via 8 broadcast b128 reads; weights pure registers.
        v2f A  = {0.0f, 0.0f}, Ab = {0.0f, 0.0f};
        v2f B  = {0.0f, 0.0f}, Bb = {0.0f, 0.0f};
        const float4* a14 = (const float4*)a1s[wv];
#pragma unroll
        for (int i = 0; i < 8; ++i) {
            float4 av = a14[i];
            v2f plo = { av.x, av.y };
            v2f phi = { av.z, av.w };
            A  = fma2(plo, w2r0[2 * i],     A);
            Ab = fma2(phi, w2r0[2 * i + 1], Ab);
            B  = fma2(plo, w2r1[2 * i],     B);
            Bb = fma2(phi, w2r1[2 * i + 1], Bb);
        }
        part[wv * 128 + c0] = A.x + A.y + Ab.x + Ab.y;
        part[wv * 128 + c1] = B.x + B.y + Bb.x + Bb.y;
        __syncthreads();                     // barrier 1

        // combine partials + bias + silu (threads 0..127, wave-uniform)
        if (tid < 128) {
            float s = part[tid] + part[128 + tid]
                    + part[256 + tid] + part[384 + tid] + b2t;
            a2s[tid] = silu_f(s);
        }
        __syncthreads();                     // barrier 2

        // L3 (replicated in all waves): output d, K-chunk g (32 wide),
        // bank-staggered broadcast b128 reads.
        v2f pp = {0.0f, 0.0f};
#pragma unroll
        for (int qq = 0; qq < 8; ++qq) {
            int qsel = (qq + 2 * g) & 7;
            float4 av = *(const float4*)&a2s[32 * g + 4 * qsel];
            pp = fma2((v2f){ av.x, av.y }, w3r[2 * qq],     pp);
            pp = fma2((v2f){ av.z, av.w }, w3r[2 * qq + 1], pp);
        }
        // cross-group combine via wave-private LDS (one round trip)
        p3s[wv * 64 + lane] = pp.x + pp.y;
        const int pb = wv * 64 + d;
        float dz = b3d + p3s[pb] + p3s[pb + 16] + p3s[pb + 32] + p3s[pb + 48];

        // One-pass LayerNorm: Σdz and Σdz² as independent DPP chains.
        float s1 = sum16_dpp(dz);
        float s2 = sum16_dpp(dz * dz);
        float m  = s1 * 0.0625f;
        float v  = fmaf(m, -m, s2 * 0.0625f);
        return (dz - m) * rsqrtf(v + 1e-5f) * lngd + lnbd;
    };

    for (int l = 0; l < 199; ++l) {
        const float dt = tvec[l + 1] - tvec[l];
        const float h  = dt * 0.125f;          // dt / K, K=8 (exact)
        const float zstart = z;
        for (int s = 0; s < 8; ++s) {
            float k1 = feval(z);
            float k2 = feval(z + h * (k1 * (float)(1.0 / 5.0)));
            float k3 = feval(z + h * ((float)(3.0 / 40.0) * k1 + (float)(9.0 / 40.0) * k2));
            float k4 = feval(z + h * ((float)(44.0 / 45.0) * k1 - (float)(56.0 / 15.0) * k2
                                    + (float)(32.0 / 9.0) * k3));
            float k5 = feval(z + h * ((float)(19372.0 / 6561.0) * k1 - (float)(25360.0 / 2187.0) * k2
                                    + (float)(64448.0 / 6561.0) * k3 - (float)(212.0 / 729.0) * k4));
            float k6 = feval(z + h * ((float)(9017.0 / 3168.0) * k1 - (float)(355.0 / 33.0) * k2
                                    + (float)(46732.0 / 5247.0) * k3 + (float)(49.0 / 176.0) * k4
                                    - (float)(5103.0 / 18656.0) * k5));
            z = z + h * ((float)(35.0 / 384.0) * k1 + (float)(500.0 / 1113.0) * k3
                       + (float)(125.0 / 192.0) * k4 - (float)(2187.0 / 6784.0) * k5
                       + (float)(11.0 / 84.0) * k6);
        }
        if (tid < 16) {
            ztraj[(l + 1) * 16 + tid] = z;
            zdiff[l * 16 + tid] = (z - zstart) / dt;
        }
    }
}

// ---------------------------------------------------------------------------
// Decoder: fused 3-layer MLP over 51200 rows. M-tile=16, 256 threads,
// 4 blocks/CU to hide the L2-bound w2 reads. (unchanged)
// ---------------------------------------------------------------------------
#define GS 516   // padded LDS stride for the 16x512 activation tile

__global__ __launch_bounds__(256, 4) void dec_kernel(
    const float* __restrict__ ztr,
    const float* __restrict__ w1, const float* __restrict__ b1,
    const float* __restrict__ w2, const float* __restrict__ b2,
    const float* __restrict__ w3, const float* __restrict__ b3,
    float* __restrict__ xhat)
{
    __shared__ __align__(16) float zt[16 * 17];
    __shared__ __align__(16) float g[16 * GS];

    const int t    = threadIdx.x;
    const int blk  = blockIdx.x;
    const int tr   = t >> 5;
    const int tc   = t & 31;
    const int row0 = blk * 16;
    const int r0   = 2 * tr;

    {
        int r = t >> 4, dd = t & 15;
        zt[r * 17 + dd] = ztr[(row0 + r) * 16 + dd];
    }
    __syncthreads();

    // Phase A: g1 = relu(z @ w1 + b1), K=16
    {
        float acc[2][16];
#pragma unroll
        for (int p = 0; p < 2; ++p)
#pragma unroll
            for (int i = 0; i < 16; ++i) acc[p][i] = 0.0f;

#pragma unroll
        for (int k = 0; k < 16; ++k) {
            float a0 = zt[(r0 + 0) * 17 + k];
            float a1 = zt[(r0 + 1) * 17 + k];
            const float4* wr = (const float4*)(w1 + k * 512 + 16 * tc);
#pragma unroll
            for (int u = 0; u < 4; ++u) {
                float4 wv = wr[u];
                acc[0][4 * u + 0] = fmaf(a0, wv.x, acc[0][4 * u + 0]);
                acc[0][4 * u + 1] = fmaf(a0, wv.y, acc[0][4 * u + 1]);
                acc[0][4 * u + 2] = fmaf(a0, wv.z, acc[0][4 * u + 2]);
                acc[0][4 * u + 3] = fmaf(a0, wv.w, acc[0][4 * u + 3]);
                acc[1][4 * u + 0] = fmaf(a1, wv.x, acc[1][4 * u + 0]);
                acc[1][4 * u + 1] = fmaf(a1, wv.y, acc[1][4 * u + 1]);
                acc[1][4 * u + 2] = fmaf(a1, wv.z, acc[1][4 * u + 2]);
                acc[1][4 * u + 3] = fmaf(a1, wv.w, acc[1][4 * u + 3]);
            }
        }
        const float4* bb = (const float4*)(b1 + 16 * tc);
#pragma unroll
        for (int u = 0; u < 4; ++u) {
            float4 bv = bb[u];
#pragma unroll
            for (int p = 0; p < 2; ++p) {
                g[(r0 + p) * GS + 16 * tc + 4 * u + 0] = fmaxf(acc[p][4 * u + 0] + bv.x, 0.0f);
                g[(r0 + p) * GS + 16 * tc + 4 * u + 1] = fmaxf(acc[p][4 * u + 1] + bv.y, 0.0f);
                g[(r0 + p) * GS + 16 * tc + 4 * u + 2] = fmaxf(acc[p][4 * u + 2] + bv.z, 0.0f);
                g[(r0 + p) * GS + 16 * tc + 4 * u + 3] = fmaxf(acc[p][4 * u + 3] + bv.w, 0.0f);
            }
        }
    }
    __syncthreads();

    // Phase B: g2 = relu(g1 @ w2 + b2), K=512
    {
        float accB[2][16];
#pragma unroll
        for (int p = 0; p < 2; ++p)
#pragma unroll
            for (int i = 0; i < 16; ++i) accB[p][i] = 0.0f;

        for (int k4 = 0; k4 < 128; ++k4) {
            float4 av0 = *(const float4*)&g[(r0 + 0) * GS + 4 * k4];
            float4 av1 = *(const float4*)&g[(r0 + 1) * GS + 4 * k4];
            float a0[4] = {av0.x, av0.y, av0.z, av0.w};
            float a1[4] = {av1.x, av1.y, av1.z, av1.w};
#pragma unroll
            for (int u = 0; u < 4; ++u) {
                const float4* wr = (const float4*)(w2 + (4 * k4 + u) * 512 + 16 * tc);
#pragma unroll
                for (int q = 0; q < 4; ++q) {
                    float4 wv = wr[q];
                    accB[0][4 * q + 0] = fmaf(a0[u], wv.x, accB[0][4 * q + 0]);
                    accB[0][4 * q + 1] = fmaf(a0[u], wv.y, accB[0][4 * q + 1]);
                    accB[0][4 * q + 2] = fmaf(a0[u], wv.z, accB[0][4 * q + 2]);
                    accB[0][4 * q + 3] = fmaf(a0[u], wv.w, accB[0][4 * q + 3]);
                    accB[1][4 * q + 0] = fmaf(a1[u], wv.x, accB[1][4 * q + 0]);
                    accB[1][4 * q + 1] = fmaf(a1[u], wv.y, accB[1][4 * q + 1]);
                    accB[1][4 * q + 2] = fmaf(a1[u], wv.z, accB[1][4 * q + 2]);
                    accB[1][4 * q + 3] = fmaf(a1[u], wv.w, accB[1][4 * q + 3]);
                }
            }
        }
        __syncthreads();
        const float4* bb = (const float4*)(b2 + 16 * tc);
#pragma unroll
        for (int u = 0; u < 4; ++u) {
            float4 bv = bb[u];
#pragma unroll
            for (int p = 0; p < 2; ++p) {
                g[(r0 + p) * GS + 16 * tc + 4 * u + 0] = fmaxf(accB[p][4 * u + 0] + bv.x, 0.0f);
                g[(r0 + p) * GS + 16 * tc + 4 * u + 1] = fmaxf(accB[p][4 * u + 1] + bv.y, 0.0f);
                g[(r0 + p) * GS + 16 * tc + 4 * u + 2] = fmaxf(accB[p][4 * u + 2] + bv.z, 0.0f);
                g[(r0 + p) * GS + 16 * tc + 4 * u + 3] = fmaxf(accB[p][4 * u + 3] + bv.w, 0.0f);
            }
        }
    }
    __syncthreads();

    // Phase C: xhat = g2 @ w3 + b3, N=256 (8 cols/thread), K=512
    {
        float accC[2][8];
#pragma unroll
        for (int p = 0; p < 2; ++p)
#pragma unroll
            for (int i = 0; i < 8; ++i) accC[p][i] = 0.0f;

        for (int k4 = 0; k4 < 128; ++k4) {
            float4 av0 = *(const float4*)&g[(r0 + 0) * GS + 4 * k4];
            float4 av1 = *(const float4*)&g[(r0 + 1) * GS + 4 * k4];
            float a0[4] = {av0.x, av0.y, av0.z, av0.w};
            float a1[4] = {av1.x, av1.y, av1.z, av1.w};
#pragma unroll
            for (int u = 0; u < 4; ++u) {
                const float4* wr = (const float4*)(w3 + (4 * k4 + u) * 256 + 8 * tc);
                float4 w0 = wr[0], w1v = wr[1];
                accC[0][0] = fmaf(a0[u], w0.x,  accC[0][0]);
                accC[0][1] = fmaf(a0[u], w0.y,  accC[0][1]);
                accC[0][2] = fmaf(a0[u], w0.z,  accC[0][2]);
                accC[0][3] = fmaf(a0[u], w0.w,  accC[0][3]);
                accC[0][4] = fmaf(a0[u], w1v.x, accC[0][4]);
                accC[0][5] = fmaf(a0[u], w1v.y, accC[0][5]);
                accC[0][6] = fmaf(a0[u], w1v.z, accC[0][6]);
                accC[0][7] = fmaf(a0[u], w1v.w, accC[0][7]);
                accC[1][0] = fmaf(a1[u], w0.x,  accC[1][0]);
                accC[1][1] = fmaf(a1[u], w0.y,  accC[1][1]);
                accC[1][2] = fmaf(a1[u], w0.z,  accC[1][2]);
                accC[1][3] = fmaf(a1[u], w0.w,  accC[1][3]);
                accC[1][4] = fmaf(a1[u], w1v.x, accC[1][4]);
                accC[1][5] = fmaf(a1[u], w1v.y, accC[1][5]);
                accC[1][6] = fmaf(a1[u], w1v.z, accC[1][6]);
                accC[1][7] = fmaf(a1[u], w1v.w, accC[1][7]);
            }
        }
        const float4* bb = (const float4*)(b3 + 8 * tc);
        float4 bv0 = bb[0], bv1 = bb[1];
#pragma unroll
        for (int p = 0; p < 2; ++p) {
            float4 o0 = make_float4(accC[p][0] + bv0.x, accC[p][1] + bv0.y,
                                    accC[p][2] + bv0.z, accC[p][3] + bv0.w);
            float4 o1 = make_float4(accC[p][4] + bv1.x, accC[p][5] + bv1.y,
                                    accC[p][6] + bv1.z, accC[p][7] + bv1.w);
            float* dst = xhat + (size_t)(row0 + r0 + p) * 256 + 8 * tc;
            *(float4*)(dst)     = o0;
            *(float4*)(dst + 4) = o1;
        }
    }
}

extern "C" void kernel_launch(void* const* d_in, const int* in_sizes, int n_in,
                              void* d_out, int out_size, void* d_ws, size_t ws_size,
                              hipStream_t stream) {
    const float* x_seq  = (const float*)d_in[0];
    const float* tvec   = (const float*)d_in[1];
    const float* eps    = (const float*)d_in[2];
    const float* enc_w1 = (const float*)d_in[3];
    const float* enc_b1 = (const float*)d_in[4];
    const float* enc_w2 = (const float*)d_in[5];
    const float* enc_b2 = (const float*)d_in[6];
    const float* enc_w3 = (const float*)d_in[7];
    const float* enc_b3 = (const float*)d_in[8];
    const float* mu_w   = (const float*)d_in[9];
    const float* mu_b   = (const float*)d_in[10];
    const float* lv_w   = (const float*)d_in[11];
    const float* lv_b   = (const float*)d_in[12];
    const float* ode_w1 = (const float*)d_in[13];
    const float* ode_b1 = (const float*)d_in[14];
    const float* ode_w2 = (const float*)d_in[15];
    const float* ode_b2 = (const float*)d_in[16];
    const float* ode_w3 = (const float*)d_in[17];
    const float* ode_b3 = (const float*)d_in[18];
    const float* ln_g   = (const float*)d_in[19];
    const float* ln_b   = (const float*)d_in[20];
    const float* dec_w1 = (const float*)d_in[21];
    const float* dec_b1 = (const float*)d_in[22];
    const float* dec_w2 = (const float*)d_in[23];
    const float* dec_b2 = (const float*)d_in[24];
    const float* dec_w3 = (const float*)d_in[25];
    const float* dec_b3 = (const float*)d_in[26];
    float* out = (float*)d_out;

    enc_kernel<<<256, 256, 0, stream>>>(x_seq, eps, enc_w1, enc_b1, enc_w2, enc_b2,
                                        enc_w3, enc_b3, mu_w, mu_b, lv_w, lv_b, out);
    ode_kernel<<<256, 256, 0, stream>>>(tvec, ode_w1, ode_b1, ode_w2, ode_b2,
                                        ode_w3, ode_b3, ln_g, ln_b, out);
    dec_kernel<<<3200, 256, 0, stream>>>(out + OFF_ZT, dec_w1, dec_b1, dec_w2, dec_b2,
                                         dec_w3, dec_b3, out);
}